// Round 1
// 286.702 us; speedup vs baseline: 1.0282x; 1.0282x over previous
//
#include <hip/hip_runtime.h>
#include <cstdint>

// ShortTermLSTM on MI355X: batched LSTM, transposed-GEMM f16 MFMA, cell fully
// in registers, fused-rcp activations in the exp2 domain (raw v_exp_f32).
// R10 324/292 steady — 2-barrier ping-pong structure. R14 292: exp2-pre-scaled
// weights + bare v_exp_f32. rocprof R14: VALUBusy 62%, MfmaUtil 28%, HBM 0.9%,
// SQ_LDS_BANK_CONFLICT 1.18e7 (~7% of cycles) -> issue/latency-bound.
// R15 (this): k-column PERMUTATION for conflict-free LDS writes + single
// barrier per step + 2L-fold + SGPR-hoisted wave indices.
//   k-map (contraction is permutation-invariant; W-pack mirrors it):
//     h unit u=(t,q), t<24 : k = 8*(t>>1) + (t&1) + 2q   (covers 0..95)
//     h unit u=96+q (t=24) : k = 96 + 2q                 (96,98,100,102)
//     x_hi*W_hi feature c  : k = 104 + 2c
//     x_lo*W_hi feature c  : k = 105 + 2c
//     x_hi*W_lo feature c  : k = 112 + 2c
//     bias_hi/lo (A=1.0)   : k = 120 / 122;   all other k: zero
//   -> every ds_write_b16 instr hits banks 4*((m+s)&7)+q: only m/m+8 2-way
//      aliasing remains (free per m136). b128 reads unchanged (balanced).
// Residual error: dropped h*W_hh_lo (~6e-5/step); measured margin ~4x.

#define H_UNITS 100
#define T_STEPS 128
#define S_BLK   16
#define NSEQ    12288
#define NBLK    (NSEQ / S_BLK)   // 768
#define NTILE   25               // 100 units / 4 per tile
#define KSTR    136              // LDS h row stride (ushorts): b128-aligned, read-balanced
#define LOG2E   1.4426950408889634f
#define TWO_L   2.8853900817779268f   // 2*log2(e)

typedef __attribute__((ext_vector_type(8))) _Float16 halfx8;
typedef __attribute__((ext_vector_type(8))) unsigned short ushortx8;
typedef __attribute__((ext_vector_type(4))) float floatx4;

__device__ __forceinline__ unsigned short f32_to_f16u(float x) {
    _Float16 h = (_Float16)x;                       // v_cvt_f16_f32 (RNE)
    return __builtin_bit_cast(unsigned short, h);
}
__device__ __forceinline__ float f16u_to_f32(unsigned short u) {
    _Float16 h = __builtin_bit_cast(_Float16, u);
    return (float)h;
}
#if __has_builtin(__builtin_amdgcn_exp2f)
__device__ __forceinline__ float fexp2(float x) { return __builtin_amdgcn_exp2f(x); }
#else
__device__ __forceinline__ float fexp2(float x) { return exp2f(x); }
#endif

// ---------------------------------------------------------------------------
// Prep: pack W (pre-scaled into exp2 domain) into MFMA A-operand fragment
// order with gate-interleaved rows, using the PERMUTED k-map above:
//   frag elem (tile,kc,lane,j) = Wsc[row n][orig(k)],  k = kc*32 + quad*8 + j.
// ---------------------------------------------------------------------------
__global__ void lstm_prep_pack(const float* __restrict__ W_ih,
                               const float* __restrict__ W_hh,
                               const float* __restrict__ b_ih,
                               const float* __restrict__ b_hh,
                               ushortx8* __restrict__ Bpack) {
    int t = blockIdx.x * 256 + threadIdx.x;   // (tile,kc,lane) flattened: 25*4*64 = 6400
    if (t >= NTILE * 4 * 64) return;
    int lane = t & 63;
    int kc   = (t >> 6) & 3;
    int tile = t >> 8;
    int m    = lane & 15;
    int n  = (m & 3) * 100 + tile * 4 + (m >> 2);   // permuted gate row (i,f,g,o = m&3)
    float sc = (n >= 200 && n < 300) ? (2.0f * LOG2E) : LOG2E;   // g rows get 2x
    int k0 = kc * 32 + ((lane >> 4) & 3) * 8;
    ushortx8 v;
#pragma unroll
    for (int j = 0; j < 8; ++j) {
        int k = k0 + j;
        unsigned short w = 0;
        if (k < 96) {
            // inverse of k = 8*(t>>1)+(t&1)+2q :  u = 8s + 4b + (r>>1)
            int u = ((k >> 3) << 3) + ((k & 1) << 2) + ((k & 7) >> 1);
            w = f32_to_f16u(W_hh[n * 100 + u] * sc);
        } else if (k < 104) {
            if (!(k & 1)) {                       // k 96,98,100,102: units 96..99
                int u = 96 + ((k - 96) >> 1);
                w = f32_to_f16u(W_hh[n * 100 + u] * sc);
            }
        } else if (k < 112) {
            // even k=104+2c: x_hi * W_hi ; odd k=105+2c: x_lo * W_hi
            int c = (k - 104) >> 1;
            w = f32_to_f16u(W_ih[n * 4 + c] * sc);
        } else if (k < 120) {
            if (!(k & 1)) {                       // k=112+2c: x_hi * W_lo
                int c = (k - 112) >> 1;
                float wf = W_ih[n * 4 + c] * sc;
                unsigned short hi = f32_to_f16u(wf);
                w = f32_to_f16u(wf - f16u_to_f32(hi));
            }
        } else if (k == 120) {                    // b_hi (scaled), A = 1.0
            float bb = (b_ih[n] + b_hh[n]) * sc;
            w = f32_to_f16u(bb);
        } else if (k == 122) {                    // b_lo (scaled), A = 1.0
            float bb = (b_ih[n] + b_hh[n]) * sc;
            unsigned short hi = f32_to_f16u(bb);
            w = f32_to_f16u(bb - f16u_to_f32(hi));
        }
        v[j] = w;
    }
    Bpack[t] = v;
}

// ---------------------------------------------------------------------------
// Main: one block = 16 sequences, full T loop. 4 waves; waves do tiles
// {w, w+4, ..., w+20}, wave0 additionally tile 24. Lane cell: unit
// j = tile*4 + quad, seq s = lane&15, acc = {i,f,g,o} in the exp2 domain.
// W kc1..3 in regs (84); kc0 in LDS. ONE barrier per step (read bufR ->
// compute -> write bufW -> s_barrier covers both cross-step hazards).
// ---------------------------------------------------------------------------
__global__ void __launch_bounds__(256, 3)
lstm_main(const float* __restrict__ x, const ushortx8* __restrict__ Bpack,
          float* __restrict__ out) {
    __shared__ __align__(16) unsigned short s_A[2][16 * KSTR];   // ping-pong, 2 x 4352 B
    __shared__ __align__(16) ushortx8       s_W[NTILE * 64];     // 25600 B, kc0 W-frags

    const int tid  = threadIdx.x;
    const int lane = tid & 63;
    const int wavu = __builtin_amdgcn_readfirstlane(tid >> 6);   // wave id in SGPR
    const int seq0 = blockIdx.x * S_BLK;
    const int m    = lane & 15;
    const int quad = lane >> 4;

    // ---- W fragments kc1..3: global -> regs, once (84 regs/wave)
    halfx8 wfrag[7][3];
#pragma unroll
    for (int it = 0; it < 7; ++it) {
        int tile = wavu + it * 4;
        if (tile < NTILE) {
#pragma unroll
            for (int kc = 0; kc < 3; ++kc)
                wfrag[it][kc] = __builtin_bit_cast(halfx8, Bpack[(tile * 4 + kc + 1) * 64 + lane]);
        }
    }
    // ---- kc0 frags (all tiles): global -> LDS, once
    for (int i = tid; i < NTILE * 64; i += 256)
        s_W[i] = Bpack[(i >> 6) * 256 + (i & 63)];

    // refresh-thread x pointer (valid for tid >= 128): (s = rt&15, cc = rt>>4)
    const int rt = tid - 128;
    const int rs = rt & 15, rc = (rt >> 4) & 7;
    const float* xb = x + (size_t)(seq0 + rs) * (T_STEPS * 4) + (rc & 3);

    // ---- zero both buffers (h(0)=0; unused k columns stay 0 forever)
    for (int i = tid; i < (2 * 16 * KSTR) / 2; i += 256)
        ((unsigned int*)s_A)[i] = 0u;
    float x0 = 0.0f;
    if (tid >= 128) x0 = xb[0];
    __syncthreads();
    // ---- x(t=0) into buf0; constant bias-select cols into BOTH buffers
    if (tid >= 128) {
        unsigned short hi = f32_to_f16u(x0);
        if (rc < 4) {
            s_A[0][rs * KSTR + 104 + 2 * rc] = hi;                        // x_hi (W_hi)
            s_A[0][rs * KSTR + 112 + 2 * rc] = hi;                        // x_hi (W_lo)
        } else {
            s_A[0][rs * KSTR + 105 + 2 * (rc - 4)] =
                f32_to_f16u(x0 - f16u_to_f32(hi));                        // x_lo (W_hi)
        }
    } else if (tid < 32) {
        s_A[tid >> 4][(tid & 15) * KSTR + 120] = 0x3C00;   // k120 = 1.0, both bufs
    } else if (tid < 64) {
        int d = tid - 32;
        s_A[d >> 4][(d & 15) * KSTR + 122] = 0x3C00;       // k122 = 1.0, both bufs
    }
    __syncthreads();   // init writes visible before first read

    float c_reg[6];   // cell state in 2*log2e domain
#pragma unroll
    for (int it = 0; it < 6; ++it) c_reg[it] = 0.0f;
    float c24 = 0.0f;

    const int rowOff = m * KSTR;
    const int aOff   = rowOff + quad * 8;
    const int q2     = quad << 1;
    // per-docell h write-column BASE (wave-uniform -> SGPR arithmetic):
    //   tile<24: 8*(tile>>1)+(tile&1) ; tile 24: 96. Lane adds quad*2.
    int hbase[7];
#pragma unroll
    for (int it = 0; it < 7; ++it) {
        int tile = wavu + it * 4;
        hbase[it] = (tile < 24) ? (((tile >> 1) << 3) + (tile & 1)) : 96;
    }

    for (int t = 0; t < T_STEPS; ++t) {
        const int bR = t & 1;
        const unsigned short* base  = s_A[bR];
        unsigned short*       baseW = s_A[bR ^ 1];

        // prefetch x(t+1) — issued before compute phase to hide latency
        float xnext = 0.0f;
        if (tid >= 128) {
            int tn = t + 1; if (tn > T_STEPS - 1) tn = T_STEPS - 1;
            xnext = xb[tn * 4];
        }

        halfx8 hh[4];
#pragma unroll
        for (int kc = 0; kc < 4; ++kc)
            hh[kc] = *(const halfx8*)(base + aOff + kc * 32);   // ds_read_b128

        const bool last = (t == T_STEPS - 1);

        auto docell = [&](int tile, int wbase, halfx8 w1, halfx8 w2, halfx8 w3, float& cm) {
            halfx8 w0 = __builtin_bit_cast(halfx8, s_W[tile * 64 + lane]);  // kc0 frag
            floatx4 acc = {0.0f, 0.0f, 0.0f, 0.0f};
            acc = __builtin_amdgcn_mfma_f32_16x16x32_f16(w0, hh[0], acc, 0, 0, 0);
            acc = __builtin_amdgcn_mfma_f32_16x16x32_f16(w1, hh[1], acc, 0, 0, 0);
            acc = __builtin_amdgcn_mfma_f32_16x16x32_f16(w2, hh[2], acc, 0, 0, 0);
            acc = __builtin_amdgcn_mfma_f32_16x16x32_f16(w3, hh[3], acc, 0, 0, 0);
            // lane = (seq s=m, unit j=tile*4+quad); acc = {i,f,g,o}, exp2 dom.
            float ei = fexp2(acc[0]);            // e^i
            float ef = fexp2(acc[1]);            // e^f
            float eg = fexp2(acc[2]);            // e^{2g}
            float eo = fexp2(acc[3]);            // e^o
            float a  = 1.0f + ei, b = 1.0f + ef;
            float d  = eg + 1.0f;
            float e2s = fmaf(eg, TWO_L, -TWO_L); // (e^{2g}-1)*2log2e  (folded scale)
            float q  = a * d;
            float r  = __builtin_amdgcn_rcpf(q * b);
            // c2 = (2log2e)*c: c2' = sigm(f)*c2 + (2log2e)*sigm(i)*tanh(g)
            float nm = fmaf(ef * q, cm, (ei * b) * e2s);
            float c2 = nm * r;
            cm = c2;
            float cc = fminf(c2, 115.0f);        // exp2 overflow guard
            float ec = fexp2(cc);                // e^{2c}
            float r2 = __builtin_amdgcn_rcpf((1.0f + eo) * (ec + 1.0f));
            float h  = (eo * (ec - 1.0f)) * r2;
            if (!last) {
                baseW[rowOff + wbase + q2] = f32_to_f16u(h);   // permuted col, 2-way-free
            } else {
                int j = tile * 4 + quad;
                out[(size_t)(seq0 + m) * H_UNITS + j] = h;
            }
        };

#pragma unroll
        for (int it = 0; it < 6; ++it)           // tiles 0..23: branch-free
            docell(wavu + it * 4, hbase[it], wfrag[it][0], wfrag[it][1], wfrag[it][2], c_reg[it]);
        if (wavu == 0)                           // tile 24: wave0 only
            docell(24, hbase[6], wfrag[6][0], wfrag[6][1], wfrag[6][2], c24);

        if (tid >= 128 && !last) {               // x(t+1) -> other buffer (permuted cols)
            unsigned short hi = f32_to_f16u(xnext);
            if (rc < 4) {
                baseW[rs * KSTR + 104 + 2 * rc] = hi;
                baseW[rs * KSTR + 112 + 2 * rc] = hi;
            } else {
                baseW[rs * KSTR + 105 + 2 * (rc - 4)] =
                    f32_to_f16u(xnext - f16u_to_f32(hi));
            }
        }
        __syncthreads();   // single barrier/step: covers write->read AND read->write
    }
}

extern "C" void kernel_launch(void* const* d_in, const int* in_sizes, int n_in,
                              void* d_out, int out_size, void* d_ws, size_t ws_size,
                              hipStream_t stream) {
    const float* x    = (const float*)d_in[0];   // [4096,3,128,4]
    const float* W_ih = (const float*)d_in[1];   // [400,4]
    const float* W_hh = (const float*)d_in[2];   // [400,100]
    const float* b_ih = (const float*)d_in[3];   // [400]
    const float* b_hh = (const float*)d_in[4];   // [400]
    ushortx8* Bpack = (ushortx8*)d_ws;           // 25*4*64*16 B = 102,400 B

    lstm_prep_pack<<<25, 256, 0, stream>>>(W_ih, W_hh, b_ih, b_hh, Bpack);
    lstm_main<<<NBLK, 256, 0, stream>>>(x, Bpack, (float*)d_out);
}